// Round 13
// baseline (191.430 us; speedup 1.0000x reference)
//
#include <hip/hip_runtime.h>
#include <hip/hip_bf16.h>
#include <math.h>
#include <stdint.h>

#define NB 128     // batch (images and captions)
#define NR 36      // regions
#define NW 64      // words
#define ND 1024    // dim
#define MT 48      // NR padded to 3 MFMA m-tiles
#define EPSF 1e-8f
#define LAM_SM 9.0f
#define LAM_LSE 6.0f
#define MARGINF 0.2f

typedef _Float16 f16;
typedef f16 f16x4 __attribute__((ext_vector_type(4)));
typedef f16 f16x8 __attribute__((ext_vector_type(8)));
typedef float f32x4 __attribute__((ext_vector_type(4)));
typedef int i32x4 __attribute__((ext_vector_type(4)));
typedef int i32x8 __attribute__((ext_vector_type(8)));

// pack 4 floats -> 4 fp8 e4m3 (OCP, HW RNE+satfinite) in one uint32
__device__ __forceinline__ uint32_t pk_fp8x4(float4 v) {
    uint32_t w = 0;
    w = __builtin_amdgcn_cvt_pk_fp8_f32(v.x, v.y, w, false);  // bytes 0,1
    w = __builtin_amdgcn_cvt_pk_fp8_f32(v.z, v.w, w, true);   // bytes 2,3
    return w;
}

// ---------------------------------------------------------------------------
// FRAGMENT-MAJOR fp8 layout (R15): one fragment = 2KB = [lane 0..63] x 32B.
//   A': ((i*8 + kc)*3 + mi)*2048 + lane*32 + b      (pad rows 36..47 zeroed)
//   B': ((j*8 + kc)*4 + nt)*2048 + lane*32 + b
// R25: 8-wave blocks (512 thr) covering 4 images x 2 captions. R12 killed the
// spill (WRITE 13.6MB->0.26MB, total 195->190); remaining quantifiable
// inefficiency is fragment delivery: 2x2 blocks stream 56KB/pair unique;
// 4x2 blocks stream 40KB/pair (-29% L1/L2 traffic). Same per-wave code,
// same 16 waves/CU (lb(512,4), 2 blocks/CU x 64KB LDS = 128 <= 160KB), no
// new barriers (epilogue wave-private). Total (the +-1us-stable metric)
// predicted 189.8 -> ~184. If unchanged, structure converged.
// ---------------------------------------------------------------------------

// ------- kernel 0: fp32 -> fp8 fragment-major + ncap + partial f32 Gram ------
// grid (NB, 18): y<14 -> convert 8 rows each; y=14..17 -> gram k-slice z=y-14.
__global__ __launch_bounds__(256) void prep_kernel(
    const float* __restrict__ im, const float* __restrict__ s,
    uint8_t* __restrict__ im8, uint8_t* __restrict__ s8, float* __restrict__ ncap,
    float* __restrict__ Mgp) {
    __shared__ __align__(16) char Gs[8192];   // gram staging [64 rows][128 B]
    const int b = blockIdx.x, y = blockIdx.y, t = threadIdx.x;

    if (y < 14) {
        const int lr = t >> 5, g = t & 31;   // local row 0..7, lane-in-row 0..31
        const int row = y * 8 + lr;          // 0..111
        if (row < MT) {
            const int mi = row >> 4, l16 = row & 15;
            uint32_t* dstd = (uint32_t*)im8;
            if (row < NR) {
                const float4* src = (const float4*)(im + ((size_t)b * NR + row) * ND);
                #pragma unroll
                for (int e = 0; e < 8; ++e) {
                    int di = g + e * 32;                 // dword index in row
                    int kc = di >> 5, q = (di >> 3) & 3, bw = di & 7;
                    size_t dst = ((size_t)(b * 8 + kc) * 3 + mi) * 512
                                 + (q * 16 + l16) * 8 + bw;
                    dstd[dst] = pk_fp8x4(src[di]);
                }
            } else {
                #pragma unroll
                for (int e = 0; e < 8; ++e) {
                    int di = g + e * 32;
                    int kc = di >> 5, q = (di >> 3) & 3, bw = di & 7;
                    size_t dst = ((size_t)(b * 8 + kc) * 3 + mi) * 512
                                 + (q * 16 + l16) * 8 + bw;
                    dstd[dst] = 0u;
                }
            }
        } else {
            const int w = row - MT;
            const int nt = w >> 4, l16 = w & 15;
            const float4* src = (const float4*)(s + ((size_t)b * NW + w) * ND);
            uint32_t* dstd = (uint32_t*)s8;
            float ss = 0.f;
            #pragma unroll
            for (int e = 0; e < 8; ++e) {
                int di = g + e * 32;
                int kc = di >> 5, q = (di >> 3) & 3, bw = di & 7;
                float4 v = src[di];
                size_t dst = ((size_t)(b * 8 + kc) * 4 + nt) * 512
                             + (q * 16 + l16) * 8 + bw;
                dstd[dst] = pk_fp8x4(v);
                ss += v.x * v.x + v.y * v.y + v.z * v.z + v.w * v.w;
            }
            #pragma unroll
            for (int off = 1; off < 32; off <<= 1) ss += __shfl_xor(ss, off, 32);
            if (g == 0) ncap[b * NW + w] = sqrtf(ss);
        }
        return;
    }

    // ---- Gram k-slice z: partial Mgp[z][b] += G[:,z*256:(z+1)*256] . G^T ----
    const int z = y - 14;                    // 0..3
    const int wave = t >> 6, lane = t & 63;
    const int quad = lane >> 4, l16 = lane & 15;
    const int nt = wave;                     // n-tile 0..3 (cols); cols >=36 end up 0
    f32x4 acc[3];
    acc[0] = (f32x4){0.f, 0.f, 0.f, 0.f};
    acc[1] = (f32x4){0.f, 0.f, 0.f, 0.f};
    acc[2] = (f32x4){0.f, 0.f, 0.f, 0.f};
    const float* imb = im + (size_t)b * NR * ND;

    for (int kk = z * 256; kk < z * 256 + 256; kk += 64) {
        for (int cidx = t; cidx < 512; cidx += 256) {
            int row = cidx >> 3, c = cidx & 7;
            f16x8 hv;
            if (row < NR) {
                const float4* sp = (const float4*)(imb + (size_t)row * ND + kk + c * 8);
                float4 v0 = sp[0], v1 = sp[1];
                hv = (f16x8){(f16)v0.x, (f16)v0.y, (f16)v0.z, (f16)v0.w,
                             (f16)v1.x, (f16)v1.y, (f16)v1.z, (f16)v1.w};
            } else {
                hv = (f16x8){(f16)0.f, (f16)0.f, (f16)0.f, (f16)0.f,
                             (f16)0.f, (f16)0.f, (f16)0.f, (f16)0.f};
            }
            *(f16x8*)(Gs + row * 128 + ((c ^ (row & 7)) * 16)) = hv;
        }
        __syncthreads();
        #pragma unroll
        for (int ks = 0; ks < 2; ++ks) {
            int brow = nt * 16 + l16;
            f16x8 bf = *(const f16x8*)(Gs + brow * 128 + (((ks * 4 + quad) ^ (brow & 7)) * 16));
            #pragma unroll
            for (int mt = 0; mt < 3; ++mt) {
                int arow = mt * 16 + l16;
                f16x8 af = *(const f16x8*)(Gs + arow * 128 + (((ks * 4 + quad) ^ (arow & 7)) * 16));
                acc[mt] = __builtin_amdgcn_mfma_f32_16x16x32_f16(af, bf, acc[mt], 0, 0, 0);
            }
        }
        __syncthreads();
    }
    float* Mp = Mgp + ((size_t)(z * NB + b)) * (MT * NW);
    #pragma unroll
    for (int mt = 0; mt < 3; ++mt) {
        #pragma unroll
        for (int r = 0; r < 4; ++r) {
            int row = mt * 16 + quad * 4 + r;
            Mp[row * NW + nt * 16 + l16] = acc[mt][r];
        }
    }
}

// ------- kernel 0b: reduce 4 f32 gram partials -> f16 Mg16 -------------------
__global__ __launch_bounds__(256) void gram_reduce_kernel(
    const float* __restrict__ Mgp, f16* __restrict__ Mg16) {
    const int b = blockIdx.x, t = threadIdx.x;
    const int n = MT * NW;                    // 3072
    for (int e = t; e < n; e += 256) {
        float s0 = Mgp[((size_t)(0 * NB + b)) * n + e];
        float s1 = Mgp[((size_t)(1 * NB + b)) * n + e];
        float s2 = Mgp[((size_t)(2 * NB + b)) * n + e];
        float s3 = Mgp[((size_t)(3 * NB + b)) * n + e];
        Mg16[(size_t)b * n + e] = (f16)((s0 + s1) + (s2 + s3));
    }
}

// ---------------- kernel B: fused GEMM + epilogue, MX-scaled fp8 ---------------
// R25 block: 512 threads = 8 waves = 4 images x 2 captions (unique traffic
// 40KB/pair vs 56 at 2x2). Wave = one (i,j) pair, acc[3][4], per-wave
// epilogue (8KB LDS each, 64KB/block, 2 blocks/CU -> 16 waves/CU unchanged).
// K-loop: mfma_scale_f32_16x16x128_f8f6f4 with UNIT scales (0x7F = 2^0).
// R18 k-loop; R24 single-acc-read two-pass epilogue; R22 quadform nt-pairs.
__global__ __launch_bounds__(512, 4) void fused_pair_kernel(
    const uint8_t* __restrict__ im8, const uint8_t* __restrict__ s8,
    const int* __restrict__ s_l, const f16* __restrict__ Mg16,
    const float* __restrict__ ncap, float* __restrict__ scores) {
    __shared__ __align__(16) char lds[65536];   // 8 waves x 8KB epilogue E^T
    const int t = threadIdx.x;
    const int wave = t >> 6, lane = t & 63;
    const int quad = lane >> 4, l16 = lane & 15;
    const int wi = wave >> 1, wj = wave & 1;    // wi 0..3, wj 0..1

    // gx fast: XCD (~lin%8) sees gx = x, x+8, ... -> B slice L2-hot;
    // gy slow: all XCDs sweep the same A window concurrently (L2/L3-hot).
    const int lin = blockIdx.x;            // 0..2047
    const int gx = lin & 63, gy = lin >> 6;   // gx 0..63, gy 0..31
    const int i = gy * 4 + wi;             // this wave's image
    const int j = gx * 2 + wj;             // this wave's caption
    const int L = s_l[j];

    f32x4 acc[3][4];
    #pragma unroll
    for (int mi = 0; mi < 3; ++mi)
        #pragma unroll
        for (int nt = 0; nt < 4; ++nt)
            acc[mi][nt] = (f32x4){0.f, 0.f, 0.f, 0.f};

    const uint8_t* Afrag = im8 + (size_t)i * (8 * 3 * 2048) + lane * 32;
    const uint8_t* Bfrag = s8 + (size_t)j * (8 * 4 * 2048) + lane * 32;

    #pragma unroll 1          // guard against unroll-induced spills (R13 lesson)
    for (int kc = 0; kc < 8; ++kc) {
        const uint8_t* Ak = Afrag + (size_t)kc * (3 * 2048);
        const uint8_t* Bk = Bfrag + (size_t)kc * (4 * 2048);
        i32x8 af0 = *(const i32x8*)(Ak);
        i32x8 af1 = *(const i32x8*)(Ak + 2048);
        i32x8 af2 = *(const i32x8*)(Ak + 4096);
        {
            i32x8 b0 = *(const i32x8*)(Bk);
            acc[0][0] = __builtin_amdgcn_mfma_scale_f32_16x16x128_f8f6f4(af0, b0, acc[0][0], 0, 0, 0, 0x7F, 0, 0x7F);
            acc[1][0] = __builtin_amdgcn_mfma_scale_f32_16x16x128_f8f6f4(af1, b0, acc[1][0], 0, 0, 0, 0x7F, 0, 0x7F);
            acc[2][0] = __builtin_amdgcn_mfma_scale_f32_16x16x128_f8f6f4(af2, b0, acc[2][0], 0, 0, 0, 0x7F, 0, 0x7F);
        }
        {
            i32x8 b1 = *(const i32x8*)(Bk + 2048);
            acc[0][1] = __builtin_amdgcn_mfma_scale_f32_16x16x128_f8f6f4(af0, b1, acc[0][1], 0, 0, 0, 0x7F, 0, 0x7F);
            acc[1][1] = __builtin_amdgcn_mfma_scale_f32_16x16x128_f8f6f4(af1, b1, acc[1][1], 0, 0, 0, 0x7F, 0, 0x7F);
            acc[2][1] = __builtin_amdgcn_mfma_scale_f32_16x16x128_f8f6f4(af2, b1, acc[2][1], 0, 0, 0, 0x7F, 0, 0x7F);
        }
        {
            i32x8 b2 = *(const i32x8*)(Bk + 4096);
            acc[0][2] = __builtin_amdgcn_mfma_scale_f32_16x16x128_f8f6f4(af0, b2, acc[0][2], 0, 0, 0, 0x7F, 0, 0x7F);
            acc[1][2] = __builtin_amdgcn_mfma_scale_f32_16x16x128_f8f6f4(af1, b2, acc[1][2], 0, 0, 0, 0x7F, 0, 0x7F);
            acc[2][2] = __builtin_amdgcn_mfma_scale_f32_16x16x128_f8f6f4(af2, b2, acc[2][2], 0, 0, 0, 0x7F, 0, 0x7F);
        }
        {
            i32x8 b3 = *(const i32x8*)(Bk + 6144);
            acc[0][3] = __builtin_amdgcn_mfma_scale_f32_16x16x128_f8f6f4(af0, b3, acc[0][3], 0, 0, 0, 0x7F, 0, 0x7F);
            acc[1][3] = __builtin_amdgcn_mfma_scale_f32_16x16x128_f8f6f4(af1, b3, acc[1][3], 0, 0, 0, 0x7F, 0, 0x7F);
            acc[2][3] = __builtin_amdgcn_mfma_scale_f32_16x16x128_f8f6f4(af2, b3, acc[2][3], 0, 0, 0, 0x7F, 0, 0x7F);
        }
    }

    // ---- wave-private epilogue (R24 two-pass; verified math R3..R12) ----
    char* waveE = lds + wave * 8192;
    {   // zero E^T rows 48..63 (chunks 6,7): pad/poison guard for quadform
        int col = lane;
        f16x8 z = {(f16)0.f,(f16)0.f,(f16)0.f,(f16)0.f,(f16)0.f,(f16)0.f,(f16)0.f,(f16)0.f};
        *(f16x8*)(waveE + col * 128 + ((6 ^ (col & 7)) * 16)) = z;
        *(f16x8*)(waveE + col * 128 + ((7 ^ (col & 7)) * 16)) = z;
    }

    // -- pass 1: read acc ONCE. lv -> f16 E^T slot; masked row sums -> rn
    //    (LAM_SM folded). acc DEAD after this loop -> no epilogue spill.
    float rn[3][4];
    #pragma unroll
    for (int mi = 0; mi < 3; ++mi) {
        float ss4[4] = {0.f, 0.f, 0.f, 0.f};
        int c = mi * 2 + (quad >> 1);
        #pragma unroll
        for (int nt = 0; nt < 4; ++nt) {
            int col = nt * 16 + l16;
            f16x4 lw;
            #pragma unroll
            for (int r = 0; r < 4; ++r) {
                float v = acc[mi][nt][r];
                float lv = v > 0.f ? v : 0.1f * v;
                lw[r] = (f16)lv;
                if (col < L) ss4[r] += lv * lv;
            }
            *(f16x4*)(waveE + col * 128 + ((c ^ (col & 7)) * 16) + (quad & 1) * 8) = lw;
        }
        #pragma unroll
        for (int r = 0; r < 4; ++r) {
            int row = mi * 16 + quad * 4 + r;
            float ss = ss4[r];
            ss += __shfl_xor(ss, 1, 64);
            ss += __shfl_xor(ss, 2, 64);
            ss += __shfl_xor(ss, 4, 64);
            ss += __shfl_xor(ss, 8, 64);
            rn[mi][r] = (row < NR) ? LAM_SM * __builtin_amdgcn_rcpf(sqrtf(ss) + EPSF) : 0.f;
        }
    }

    // -- pass 2: lv -> e in-place (E^T); cs/nu partials (v = lv>0?lv:10*lv) --
    float cs[4] = {0.f, 0.f, 0.f, 0.f}, nu[4] = {0.f, 0.f, 0.f, 0.f};
    #pragma unroll
    for (int mi = 0; mi < 3; ++mi) {
        int c = mi * 2 + (quad >> 1);
        #pragma unroll
        for (int nt = 0; nt < 4; ++nt) {
            int col = nt * 16 + l16;
            char* slot = waveE + col * 128 + ((c ^ (col & 7)) * 16) + (quad & 1) * 8;
            f16x4 lw = *(const f16x4*)slot;
            f16x4 ew;
            #pragma unroll
            for (int r = 0; r < 4; ++r) {
                float lv = (float)lw[r];
                float e = __expf((col < L) ? lv * rn[mi][r] : 0.f);
                ew[r] = (f16)e;
                if (mi * 16 + quad * 4 + r < NR) {
                    cs[nt] += e;
                    float v = lv > 0.f ? lv : 10.f * lv;
                    nu[nt] += e * v;
                }
            }
            *(f16x4*)slot = ew;
        }
    }
    #pragma unroll
    for (int nt = 0; nt < 4; ++nt) {
        cs[nt] += __shfl_xor(cs[nt], 16, 64); cs[nt] += __shfl_xor(cs[nt], 32, 64);
        nu[nt] += __shfl_xor(nu[nt], 16, 64); nu[nt] += __shfl_xor(nu[nt], 32, 64);
    }

    // -- quadform mi-at-a-time, nt-PAIRS (R22): y[2] live (8 regs) --
    const f16* Mi = Mg16 + (size_t)i * (MT * NW);
    float qf[4] = {0.f, 0.f, 0.f, 0.f};
    #pragma unroll
    for (int mi = 0; mi < 3; ++mi) {
        int row0 = mi * 16 + quad * 4;
        int cch = row0 >> 3, sub = (row0 >> 2) & 1;
        #pragma unroll
        for (int np = 0; np < 2; ++np) {
            f32x4 y[2];
            y[0] = (f32x4){0.f, 0.f, 0.f, 0.f};
            y[1] = (f32x4){0.f, 0.f, 0.f, 0.f};
            #pragma unroll
            for (int ks = 0; ks < 2; ++ks) {
                f16x8 aq = *(const f16x8*)(Mi + (mi * 16 + l16) * NW + ks * 32 + quad * 8);
                #pragma unroll
                for (int n2 = 0; n2 < 2; ++n2) {
                    int nt = np * 2 + n2;
                    int col = nt * 16 + l16;
                    int pch = (ks * 4 + quad) ^ (col & 7);
                    f16x8 bq = *(const f16x8*)(waveE + col * 128 + pch * 16);
                    y[n2] = __builtin_amdgcn_mfma_f32_16x16x32_f16(aq, bq, y[n2], 0, 0, 0);
                }
            }
            #pragma unroll
            for (int n2 = 0; n2 < 2; ++n2) {
                int nt = np * 2 + n2;
                int col = nt * 16 + l16;
                f16x4 ev = *(const f16x4*)(waveE + col * 128 + ((cch ^ (col & 7)) * 16) + sub * 8);
                #pragma unroll
                for (int r = 0; r < 4; ++r) qf[nt] += y[n2][r] * (float)ev[r];
            }
        }
    }
    #pragma unroll
    for (int nt = 0; nt < 4; ++nt) {
        qf[nt] += __shfl_xor(qf[nt], 16, 64); qf[nt] += __shfl_xor(qf[nt], 32, 64);
    }
    // -- finalize: cosine row values, LSE over words, write score --
    // rcp-based divides (v_rcp_f32): ~1ulp, noise vs the fp8 core.
    float lse = 0.f;
    #pragma unroll
    for (int nt = 0; nt < 4; ++nt) {
        int col = nt * 16 + l16;
        float rcs  = __builtin_amdgcn_rcpf(cs[nt]);
        float num  = nu[nt] * rcs;
        float nwei = sqrtf(fmaxf(qf[nt], 0.f)) * rcs;
        float nc   = ncap[j * NW + col];
        float rowv = num * __builtin_amdgcn_rcpf(fmaxf(nc * nwei, EPSF));
        lse += (col < L) ? __expf(LAM_LSE * rowv) : 0.f;
    }
    lse += __shfl_xor(lse, 1, 64);
    lse += __shfl_xor(lse, 2, 64);
    lse += __shfl_xor(lse, 4, 64);
    lse += __shfl_xor(lse, 8, 64);
    if (lane == 0) scores[i * NB + j] = __logf(lse) / LAM_LSE;
}

// ---------------- kernel C: contrastive loss reduction (LDS-staged S) ------------
// R20: row-max (threads 0..127) and col-max (threads 128..255) in parallel;
// skewed row walk (R16) kept.
__global__ __launch_bounds__(256) void loss_kernel(const float* __restrict__ S,
                                                   float* __restrict__ out) {
    __shared__ __align__(16) float Sl[NB * NB];
    __shared__ float pr[NB], pc[NB];
    __shared__ float wsum[2];
    int t = threadIdx.x;
    for (int c = t; c < (NB * NB) / 4; c += 256)
        ((float4*)Sl)[c] = ((const float4*)S)[c];
    __syncthreads();
    if (t < NB) {
        float dii = Sl[t * NB + t];
        float rmax = 0.f;
        for (int k = 0; k < NB; ++k) {
            int kk = (k + t) & (NB - 1);       // skewed: bank = (t+kk)%32, distinct/lane
            if (kk != t) {
                float vs = MARGINF + Sl[t * NB + kk] - dii;
                rmax = fmaxf(rmax, fmaxf(vs, 0.f));
            }
        }
        pr[t] = rmax;
    } else {
        int tc = t - NB;
        float dii = Sl[tc * NB + tc];
        float cmax = 0.f;
        for (int k = 0; k < NB; ++k) {
            if (k != tc) {
                float vi = MARGINF + Sl[k * NB + tc] - dii;   // lane-coalesced
                cmax = fmaxf(cmax, fmaxf(vi, 0.f));
            }
        }
        pc[tc] = cmax;
    }
    __syncthreads();
    if (t < NB) {
        float v = pr[t] + pc[t];
        #pragma unroll
        for (int off = 1; off < 64; off <<= 1) v += __shfl_xor(v, off, 64);
        if ((t & 63) == 0) wsum[t >> 6] = v;
    }
    __syncthreads();
    if (t == 0) out[0] = wsum[0] + wsum[1];
}

extern "C" void kernel_launch(void* const* d_in, const int* in_sizes, int n_in,
                              void* d_out, int out_size, void* d_ws, size_t ws_size,
                              hipStream_t stream) {
    const float* im  = (const float*)d_in[0];
    const float* s   = (const float*)d_in[1];
    const int*   s_l = (const int*)d_in[2];

    float*   scores = (float*)d_ws;                        // 16384 f32
    float*   ncap   = scores + NB * NB;                    // 8192 f32
    f16*     Mg16   = (f16*)(ncap + NB * NW);              // 128*48*64 f16
    uint8_t* im8    = (uint8_t*)(Mg16 + (size_t)NB * MT * NW);  // 128*48*1024 fp8 (frag-major)
    uint8_t* s8     = im8 + (size_t)NB * MT * ND;          // 128*64*1024 fp8 (frag-major)
    float*   Mgp    = (float*)(s8 + (size_t)NB * NW * ND); // 4*128*3072 f32 partial grams

    dim3 pgrid(NB, 18);
    prep_kernel<<<pgrid, 256, 0, stream>>>(im, s, im8, s8, ncap, Mgp);
    gram_reduce_kernel<<<NB, 256, 0, stream>>>(Mgp, Mg16);
    fused_pair_kernel<<<2048, 512, 0, stream>>>(im8, s8, s_l, Mg16, ncap, scores);
    loss_kernel<<<1, 256, 0, stream>>>(scores, (float*)d_out);
}

// Round 14
// 188.820 us; speedup vs baseline: 1.0138x; 1.0138x over previous
//
#include <hip/hip_runtime.h>
#include <hip/hip_bf16.h>
#include <math.h>
#include <stdint.h>

#define NB 128     // batch (images and captions)
#define NR 36      // regions
#define NW 64      // words
#define ND 1024    // dim
#define MT 48      // NR padded to 3 MFMA m-tiles
#define EPSF 1e-8f
#define LAM_SM 9.0f
#define LAM_LSE 6.0f
#define MARGINF 0.2f

typedef _Float16 f16;
typedef f16 f16x4 __attribute__((ext_vector_type(4)));
typedef f16 f16x8 __attribute__((ext_vector_type(8)));
typedef float f32x4 __attribute__((ext_vector_type(4)));
typedef int i32x4 __attribute__((ext_vector_type(4)));
typedef int i32x8 __attribute__((ext_vector_type(8)));

// pack 4 floats -> 4 fp8 e4m3 (OCP, HW RNE+satfinite) in one uint32
__device__ __forceinline__ uint32_t pk_fp8x4(float4 v) {
    uint32_t w = 0;
    w = __builtin_amdgcn_cvt_pk_fp8_f32(v.x, v.y, w, false);  // bytes 0,1
    w = __builtin_amdgcn_cvt_pk_fp8_f32(v.z, v.w, w, true);   // bytes 2,3
    return w;
}

// ---------------------------------------------------------------------------
// FRAGMENT-MAJOR fp8 layout (R15): one fragment = 2KB = [lane 0..63] x 32B.
//   A': ((i*8 + kc)*3 + mi)*2048 + lane*32 + b      (pad rows 36..47 zeroed)
//   B': ((j*8 + kc)*4 + nt)*2048 + lane*32 + b
// R26 = R12 verbatim (session-best 189.8us). R13's 4x2 block was null/slight
// regression (FETCH unchanged — the fp8 set is L2/L3-resident; per-wave L1
// traffic isn't on the critical path) -> fused structure converged:
// spill-free, occupancy at the 16-wave/CU register-class cap, no pipe >56%.
// Config: R23 gram 4x split, R18 k-loop (af-resident/bf-streamed, lb(256,4)),
// R24 single-acc-read two-pass epilogue, R22 quadform nt-pairs, R20 loss.
// ---------------------------------------------------------------------------

// ------- kernel 0: fp32 -> fp8 fragment-major + ncap + partial f32 Gram ------
// grid (NB, 18): y<14 -> convert 8 rows each; y=14..17 -> gram k-slice z=y-14.
__global__ __launch_bounds__(256) void prep_kernel(
    const float* __restrict__ im, const float* __restrict__ s,
    uint8_t* __restrict__ im8, uint8_t* __restrict__ s8, float* __restrict__ ncap,
    float* __restrict__ Mgp) {
    __shared__ __align__(16) char Gs[8192];   // gram staging [64 rows][128 B]
    const int b = blockIdx.x, y = blockIdx.y, t = threadIdx.x;

    if (y < 14) {
        const int lr = t >> 5, g = t & 31;   // local row 0..7, lane-in-row 0..31
        const int row = y * 8 + lr;          // 0..111
        if (row < MT) {
            const int mi = row >> 4, l16 = row & 15;
            uint32_t* dstd = (uint32_t*)im8;
            if (row < NR) {
                const float4* src = (const float4*)(im + ((size_t)b * NR + row) * ND);
                #pragma unroll
                for (int e = 0; e < 8; ++e) {
                    int di = g + e * 32;                 // dword index in row
                    int kc = di >> 5, q = (di >> 3) & 3, bw = di & 7;
                    size_t dst = ((size_t)(b * 8 + kc) * 3 + mi) * 512
                                 + (q * 16 + l16) * 8 + bw;
                    dstd[dst] = pk_fp8x4(src[di]);
                }
            } else {
                #pragma unroll
                for (int e = 0; e < 8; ++e) {
                    int di = g + e * 32;
                    int kc = di >> 5, q = (di >> 3) & 3, bw = di & 7;
                    size_t dst = ((size_t)(b * 8 + kc) * 3 + mi) * 512
                                 + (q * 16 + l16) * 8 + bw;
                    dstd[dst] = 0u;
                }
            }
        } else {
            const int w = row - MT;
            const int nt = w >> 4, l16 = w & 15;
            const float4* src = (const float4*)(s + ((size_t)b * NW + w) * ND);
            uint32_t* dstd = (uint32_t*)s8;
            float ss = 0.f;
            #pragma unroll
            for (int e = 0; e < 8; ++e) {
                int di = g + e * 32;
                int kc = di >> 5, q = (di >> 3) & 3, bw = di & 7;
                float4 v = src[di];
                size_t dst = ((size_t)(b * 8 + kc) * 4 + nt) * 512
                             + (q * 16 + l16) * 8 + bw;
                dstd[dst] = pk_fp8x4(v);
                ss += v.x * v.x + v.y * v.y + v.z * v.z + v.w * v.w;
            }
            #pragma unroll
            for (int off = 1; off < 32; off <<= 1) ss += __shfl_xor(ss, off, 32);
            if (g == 0) ncap[b * NW + w] = sqrtf(ss);
        }
        return;
    }

    // ---- Gram k-slice z: partial Mgp[z][b] += G[:,z*256:(z+1)*256] . G^T ----
    const int z = y - 14;                    // 0..3
    const int wave = t >> 6, lane = t & 63;
    const int quad = lane >> 4, l16 = lane & 15;
    const int nt = wave;                     // n-tile 0..3 (cols); cols >=36 end up 0
    f32x4 acc[3];
    acc[0] = (f32x4){0.f, 0.f, 0.f, 0.f};
    acc[1] = (f32x4){0.f, 0.f, 0.f, 0.f};
    acc[2] = (f32x4){0.f, 0.f, 0.f, 0.f};
    const float* imb = im + (size_t)b * NR * ND;

    for (int kk = z * 256; kk < z * 256 + 256; kk += 64) {
        for (int cidx = t; cidx < 512; cidx += 256) {
            int row = cidx >> 3, c = cidx & 7;
            f16x8 hv;
            if (row < NR) {
                const float4* sp = (const float4*)(imb + (size_t)row * ND + kk + c * 8);
                float4 v0 = sp[0], v1 = sp[1];
                hv = (f16x8){(f16)v0.x, (f16)v0.y, (f16)v0.z, (f16)v0.w,
                             (f16)v1.x, (f16)v1.y, (f16)v1.z, (f16)v1.w};
            } else {
                hv = (f16x8){(f16)0.f, (f16)0.f, (f16)0.f, (f16)0.f,
                             (f16)0.f, (f16)0.f, (f16)0.f, (f16)0.f};
            }
            *(f16x8*)(Gs + row * 128 + ((c ^ (row & 7)) * 16)) = hv;
        }
        __syncthreads();
        #pragma unroll
        for (int ks = 0; ks < 2; ++ks) {
            int brow = nt * 16 + l16;
            f16x8 bf = *(const f16x8*)(Gs + brow * 128 + (((ks * 4 + quad) ^ (brow & 7)) * 16));
            #pragma unroll
            for (int mt = 0; mt < 3; ++mt) {
                int arow = mt * 16 + l16;
                f16x8 af = *(const f16x8*)(Gs + arow * 128 + (((ks * 4 + quad) ^ (arow & 7)) * 16));
                acc[mt] = __builtin_amdgcn_mfma_f32_16x16x32_f16(af, bf, acc[mt], 0, 0, 0);
            }
        }
        __syncthreads();
    }
    float* Mp = Mgp + ((size_t)(z * NB + b)) * (MT * NW);
    #pragma unroll
    for (int mt = 0; mt < 3; ++mt) {
        #pragma unroll
        for (int r = 0; r < 4; ++r) {
            int row = mt * 16 + quad * 4 + r;
            Mp[row * NW + nt * 16 + l16] = acc[mt][r];
        }
    }
}

// ------- kernel 0b: reduce 4 f32 gram partials -> f16 Mg16 -------------------
__global__ __launch_bounds__(256) void gram_reduce_kernel(
    const float* __restrict__ Mgp, f16* __restrict__ Mg16) {
    const int b = blockIdx.x, t = threadIdx.x;
    const int n = MT * NW;                    // 3072
    for (int e = t; e < n; e += 256) {
        float s0 = Mgp[((size_t)(0 * NB + b)) * n + e];
        float s1 = Mgp[((size_t)(1 * NB + b)) * n + e];
        float s2 = Mgp[((size_t)(2 * NB + b)) * n + e];
        float s3 = Mgp[((size_t)(3 * NB + b)) * n + e];
        Mg16[(size_t)b * n + e] = (f16)((s0 + s1) + (s2 + s3));
    }
}

// ---------------- kernel B: fused GEMM + epilogue, MX-scaled fp8 ---------------
// Block tile 96x128 = 2 images x 2 captions; wave = one pair (acc[3][4]).
// K-loop: mfma_scale_f32_16x16x128_f8f6f4 with UNIT scales (0x7F = 2^0).
// R18 k-loop; R24 single-acc-read two-pass epilogue; R22 quadform nt-pairs.
__global__ __launch_bounds__(256, 4) void fused_pair_kernel(
    const uint8_t* __restrict__ im8, const uint8_t* __restrict__ s8,
    const int* __restrict__ s_l, const f16* __restrict__ Mg16,
    const float* __restrict__ ncap, float* __restrict__ scores) {
    __shared__ __align__(16) char lds[32768];   // epilogue E^T only (8KB/wave)
    const int t = threadIdx.x;
    const int wave = t >> 6, lane = t & 63;
    const int quad = lane >> 4, l16 = lane & 15;
    const int wi = wave >> 1, wj = wave & 1;

    // gx fast: XCD (~lin%8) sees gx = x, x+8, ... -> B slice (16 captions) L2-hot;
    // gy slow: all XCDs sweep the same A window concurrently (L2/L3-hot).
    const int lin = blockIdx.x;            // 0..4095
    const int gx = lin & 63, gy = lin >> 6;
    const int i = gy * 2 + wi;             // this wave's image
    const int j = gx * 2 + wj;             // this wave's caption
    const int L = s_l[j];

    f32x4 acc[3][4];
    #pragma unroll
    for (int mi = 0; mi < 3; ++mi)
        #pragma unroll
        for (int nt = 0; nt < 4; ++nt)
            acc[mi][nt] = (f32x4){0.f, 0.f, 0.f, 0.f};

    const uint8_t* Afrag = im8 + (size_t)i * (8 * 3 * 2048) + lane * 32;
    const uint8_t* Bfrag = s8 + (size_t)j * (8 * 4 * 2048) + lane * 32;

    #pragma unroll 1          // guard against unroll-induced spills (R13 lesson)
    for (int kc = 0; kc < 8; ++kc) {
        const uint8_t* Ak = Afrag + (size_t)kc * (3 * 2048);
        const uint8_t* Bk = Bfrag + (size_t)kc * (4 * 2048);
        i32x8 af0 = *(const i32x8*)(Ak);
        i32x8 af1 = *(const i32x8*)(Ak + 2048);
        i32x8 af2 = *(const i32x8*)(Ak + 4096);
        {
            i32x8 b0 = *(const i32x8*)(Bk);
            acc[0][0] = __builtin_amdgcn_mfma_scale_f32_16x16x128_f8f6f4(af0, b0, acc[0][0], 0, 0, 0, 0x7F, 0, 0x7F);
            acc[1][0] = __builtin_amdgcn_mfma_scale_f32_16x16x128_f8f6f4(af1, b0, acc[1][0], 0, 0, 0, 0x7F, 0, 0x7F);
            acc[2][0] = __builtin_amdgcn_mfma_scale_f32_16x16x128_f8f6f4(af2, b0, acc[2][0], 0, 0, 0, 0x7F, 0, 0x7F);
        }
        {
            i32x8 b1 = *(const i32x8*)(Bk + 2048);
            acc[0][1] = __builtin_amdgcn_mfma_scale_f32_16x16x128_f8f6f4(af0, b1, acc[0][1], 0, 0, 0, 0x7F, 0, 0x7F);
            acc[1][1] = __builtin_amdgcn_mfma_scale_f32_16x16x128_f8f6f4(af1, b1, acc[1][1], 0, 0, 0, 0x7F, 0, 0x7F);
            acc[2][1] = __builtin_amdgcn_mfma_scale_f32_16x16x128_f8f6f4(af2, b1, acc[2][1], 0, 0, 0, 0x7F, 0, 0x7F);
        }
        {
            i32x8 b2 = *(const i32x8*)(Bk + 4096);
            acc[0][2] = __builtin_amdgcn_mfma_scale_f32_16x16x128_f8f6f4(af0, b2, acc[0][2], 0, 0, 0, 0x7F, 0, 0x7F);
            acc[1][2] = __builtin_amdgcn_mfma_scale_f32_16x16x128_f8f6f4(af1, b2, acc[1][2], 0, 0, 0, 0x7F, 0, 0x7F);
            acc[2][2] = __builtin_amdgcn_mfma_scale_f32_16x16x128_f8f6f4(af2, b2, acc[2][2], 0, 0, 0, 0x7F, 0, 0x7F);
        }
        {
            i32x8 b3 = *(const i32x8*)(Bk + 6144);
            acc[0][3] = __builtin_amdgcn_mfma_scale_f32_16x16x128_f8f6f4(af0, b3, acc[0][3], 0, 0, 0, 0x7F, 0, 0x7F);
            acc[1][3] = __builtin_amdgcn_mfma_scale_f32_16x16x128_f8f6f4(af1, b3, acc[1][3], 0, 0, 0, 0x7F, 0, 0x7F);
            acc[2][3] = __builtin_amdgcn_mfma_scale_f32_16x16x128_f8f6f4(af2, b3, acc[2][3], 0, 0, 0, 0x7F, 0, 0x7F);
        }
    }

    // ---- wave-private epilogue (R24 two-pass; verified math R3..R12) ----
    char* waveE = lds + wave * 8192;
    {   // zero E^T rows 48..63 (chunks 6,7): pad/poison guard for quadform
        int col = lane;
        f16x8 z = {(f16)0.f,(f16)0.f,(f16)0.f,(f16)0.f,(f16)0.f,(f16)0.f,(f16)0.f,(f16)0.f};
        *(f16x8*)(waveE + col * 128 + ((6 ^ (col & 7)) * 16)) = z;
        *(f16x8*)(waveE + col * 128 + ((7 ^ (col & 7)) * 16)) = z;
    }

    // -- pass 1: read acc ONCE. lv -> f16 E^T slot; masked row sums -> rn
    //    (LAM_SM folded). acc DEAD after this loop -> epilogue spill gone.
    float rn[3][4];
    #pragma unroll
    for (int mi = 0; mi < 3; ++mi) {
        float ss4[4] = {0.f, 0.f, 0.f, 0.f};
        int c = mi * 2 + (quad >> 1);
        #pragma unroll
        for (int nt = 0; nt < 4; ++nt) {
            int col = nt * 16 + l16;
            f16x4 lw;
            #pragma unroll
            for (int r = 0; r < 4; ++r) {
                float v = acc[mi][nt][r];
                float lv = v > 0.f ? v : 0.1f * v;
                lw[r] = (f16)lv;
                if (col < L) ss4[r] += lv * lv;
            }
            *(f16x4*)(waveE + col * 128 + ((c ^ (col & 7)) * 16) + (quad & 1) * 8) = lw;
        }
        #pragma unroll
        for (int r = 0; r < 4; ++r) {
            int row = mi * 16 + quad * 4 + r;
            float ss = ss4[r];
            ss += __shfl_xor(ss, 1, 64);
            ss += __shfl_xor(ss, 2, 64);
            ss += __shfl_xor(ss, 4, 64);
            ss += __shfl_xor(ss, 8, 64);
            rn[mi][r] = (row < NR) ? LAM_SM * __builtin_amdgcn_rcpf(sqrtf(ss) + EPSF) : 0.f;
        }
    }

    // -- pass 2: lv -> e in-place (E^T); cs/nu partials (v = lv>0?lv:10*lv) --
    float cs[4] = {0.f, 0.f, 0.f, 0.f}, nu[4] = {0.f, 0.f, 0.f, 0.f};
    #pragma unroll
    for (int mi = 0; mi < 3; ++mi) {
        int c = mi * 2 + (quad >> 1);
        #pragma unroll
        for (int nt = 0; nt < 4; ++nt) {
            int col = nt * 16 + l16;
            char* slot = waveE + col * 128 + ((c ^ (col & 7)) * 16) + (quad & 1) * 8;
            f16x4 lw = *(const f16x4*)slot;
            f16x4 ew;
            #pragma unroll
            for (int r = 0; r < 4; ++r) {
                float lv = (float)lw[r];
                float e = __expf((col < L) ? lv * rn[mi][r] : 0.f);
                ew[r] = (f16)e;
                if (mi * 16 + quad * 4 + r < NR) {
                    cs[nt] += e;
                    float v = lv > 0.f ? lv : 10.f * lv;
                    nu[nt] += e * v;
                }
            }
            *(f16x4*)slot = ew;
        }
    }
    #pragma unroll
    for (int nt = 0; nt < 4; ++nt) {
        cs[nt] += __shfl_xor(cs[nt], 16, 64); cs[nt] += __shfl_xor(cs[nt], 32, 64);
        nu[nt] += __shfl_xor(nu[nt], 16, 64); nu[nt] += __shfl_xor(nu[nt], 32, 64);
    }

    // -- quadform mi-at-a-time, nt-PAIRS (R22): y[2] live (8 regs) --
    const f16* Mi = Mg16 + (size_t)i * (MT * NW);
    float qf[4] = {0.f, 0.f, 0.f, 0.f};
    #pragma unroll
    for (int mi = 0; mi < 3; ++mi) {
        int row0 = mi * 16 + quad * 4;
        int cch = row0 >> 3, sub = (row0 >> 2) & 1;
        #pragma unroll
        for (int np = 0; np < 2; ++np) {
            f32x4 y[2];
            y[0] = (f32x4){0.f, 0.f, 0.f, 0.f};
            y[1] = (f32x4){0.f, 0.f, 0.f, 0.f};
            #pragma unroll
            for (int ks = 0; ks < 2; ++ks) {
                f16x8 aq = *(const f16x8*)(Mi + (mi * 16 + l16) * NW + ks * 32 + quad * 8);
                #pragma unroll
                for (int n2 = 0; n2 < 2; ++n2) {
                    int nt = np * 2 + n2;
                    int col = nt * 16 + l16;
                    int pch = (ks * 4 + quad) ^ (col & 7);
                    f16x8 bq = *(const f16x8*)(waveE + col * 128 + pch * 16);
                    y[n2] = __builtin_amdgcn_mfma_f32_16x16x32_f16(aq, bq, y[n2], 0, 0, 0);
                }
            }
            #pragma unroll
            for (int n2 = 0; n2 < 2; ++n2) {
                int nt = np * 2 + n2;
                int col = nt * 16 + l16;
                f16x4 ev = *(const f16x4*)(waveE + col * 128 + ((cch ^ (col & 7)) * 16) + sub * 8);
                #pragma unroll
                for (int r = 0; r < 4; ++r) qf[nt] += y[n2][r] * (float)ev[r];
            }
        }
    }
    #pragma unroll
    for (int nt = 0; nt < 4; ++nt) {
        qf[nt] += __shfl_xor(qf[nt], 16, 64); qf[nt] += __shfl_xor(qf[nt], 32, 64);
    }
    // -- finalize: cosine row values, LSE over words, write score --
    // rcp-based divides (v_rcp_f32): ~1ulp, noise vs the fp8 core.
    float lse = 0.f;
    #pragma unroll
    for (int nt = 0; nt < 4; ++nt) {
        int col = nt * 16 + l16;
        float rcs  = __builtin_amdgcn_rcpf(cs[nt]);
        float num  = nu[nt] * rcs;
        float nwei = sqrtf(fmaxf(qf[nt], 0.f)) * rcs;
        float nc   = ncap[j * NW + col];
        float rowv = num * __builtin_amdgcn_rcpf(fmaxf(nc * nwei, EPSF));
        lse += (col < L) ? __expf(LAM_LSE * rowv) : 0.f;
    }
    lse += __shfl_xor(lse, 1, 64);
    lse += __shfl_xor(lse, 2, 64);
    lse += __shfl_xor(lse, 4, 64);
    lse += __shfl_xor(lse, 8, 64);
    if (lane == 0) scores[i * NB + j] = __logf(lse) / LAM_LSE;
}

// ---------------- kernel C: contrastive loss reduction (LDS-staged S) ------------
// R20: row-max (threads 0..127) and col-max (threads 128..255) in parallel;
// skewed row walk (R16) kept.
__global__ __launch_bounds__(256) void loss_kernel(const float* __restrict__ S,
                                                   float* __restrict__ out) {
    __shared__ __align__(16) float Sl[NB * NB];
    __shared__ float pr[NB], pc[NB];
    __shared__ float wsum[2];
    int t = threadIdx.x;
    for (int c = t; c < (NB * NB) / 4; c += 256)
        ((float4*)Sl)[c] = ((const float4*)S)[c];
    __syncthreads();
    if (t < NB) {
        float dii = Sl[t * NB + t];
        float rmax = 0.f;
        for (int k = 0; k < NB; ++k) {
            int kk = (k + t) & (NB - 1);       // skewed: bank = (t+kk)%32, distinct/lane
            if (kk != t) {
                float vs = MARGINF + Sl[t * NB + kk] - dii;
                rmax = fmaxf(rmax, fmaxf(vs, 0.f));
            }
        }
        pr[t] = rmax;
    } else {
        int tc = t - NB;
        float dii = Sl[tc * NB + tc];
        float cmax = 0.f;
        for (int k = 0; k < NB; ++k) {
            if (k != tc) {
                float vi = MARGINF + Sl[k * NB + tc] - dii;   // lane-coalesced
                cmax = fmaxf(cmax, fmaxf(vi, 0.f));
            }
        }
        pc[tc] = cmax;
    }
    __syncthreads();
    if (t < NB) {
        float v = pr[t] + pc[t];
        #pragma unroll
        for (int off = 1; off < 64; off <<= 1) v += __shfl_xor(v, off, 64);
        if ((t & 63) == 0) wsum[t >> 6] = v;
    }
    __syncthreads();
    if (t == 0) out[0] = wsum[0] + wsum[1];
}

extern "C" void kernel_launch(void* const* d_in, const int* in_sizes, int n_in,
                              void* d_out, int out_size, void* d_ws, size_t ws_size,
                              hipStream_t stream) {
    const float* im  = (const float*)d_in[0];
    const float* s   = (const float*)d_in[1];
    const int*   s_l = (const int*)d_in[2];

    float*   scores = (float*)d_ws;                        // 16384 f32
    float*   ncap   = scores + NB * NB;                    // 8192 f32
    f16*     Mg16   = (f16*)(ncap + NB * NW);              // 128*48*64 f16
    uint8_t* im8    = (uint8_t*)(Mg16 + (size_t)NB * MT * NW);  // 128*48*1024 fp8 (frag-major)
    uint8_t* s8     = im8 + (size_t)NB * MT * ND;          // 128*64*1024 fp8 (frag-major)
    float*   Mgp    = (float*)(s8 + (size_t)NB * NW * ND); // 4*128*3072 f32 partial grams

    dim3 pgrid(NB, 18);
    prep_kernel<<<pgrid, 256, 0, stream>>>(im, s, im8, s8, ncap, Mgp);
    gram_reduce_kernel<<<NB, 256, 0, stream>>>(Mgp, Mg16);
    fused_pair_kernel<<<4096, 256, 0, stream>>>(im8, s8, s_l, Mg16, ncap, scores);
    loss_kernel<<<1, 256, 0, stream>>>(scores, (float*)d_out);
}